// Round 4
// baseline (304.280 us; speedup 1.0000x reference)
//
#include <hip/hip_runtime.h>
#include <hip/hip_bf16.h>
#include <math.h>

// Problem constants
constexpr int Bn     = 2;
constexpr int Lseq   = 1024;
constexpr int DM     = 512;    // d_model
constexpr int DI     = 1024;   // d_inner
constexpr int DS     = 64;     // d_state
constexpr int RNK    = 32;     // dt_rank
constexpr int NROWS  = Bn * Lseq;  // 2048
constexpr int XDBW   = RNK + 2 * DS; // 160
constexpr int CH     = 64;     // scan chunk length
constexpr int NC     = Lseq / CH;  // 16 chunks

typedef __attribute__((ext_vector_type(4))) float floatx4;
typedef __attribute__((ext_vector_type(8))) short shortx8;

__device__ __forceinline__ float silu_f(float v) {
    return v / (1.f + __expf(-v));
}

__device__ __forceinline__ float rdl(float v, int l) {
    return __int_as_float(__builtin_amdgcn_readlane(__float_as_int(v), l));
}

// v += shfl_xor(v,1); v += shfl_xor(v,2) via quad_perm DPP (pure VALU).
// Result valid in all lanes; lanes s%4==0 hold sum over the quad {s..s+3}.
__device__ __forceinline__ float dpp_add2(float v) {
    int x = __float_as_int(v);
    v += __int_as_float(__builtin_amdgcn_update_dpp(0, x, 0xB1, 0xF, 0xF, true)); // qperm(1,0,3,2)
    x = __float_as_int(v);
    v += __int_as_float(__builtin_amdgcn_update_dpp(0, x, 0x4E, 0xF, 0xF, true)); // qperm(2,3,0,1)
    return v;
}

// ---------------- LayerNorm -> bf16 ----------------
__global__ void ln_kernel(const float* __restrict__ x, const float* __restrict__ g,
                          const float* __restrict__ be, __hip_bfloat16* __restrict__ xn) {
    int row = blockIdx.x;
    int tid = threadIdx.x;
    const float* xr = x + (size_t)row * DM;
    float v0 = xr[tid], v1 = xr[tid + 256];
    float s = v0 + v1, sq = v0 * v0 + v1 * v1;
    #pragma unroll
    for (int o = 1; o < 64; o <<= 1) {
        s  += __shfl_xor(s, o);
        sq += __shfl_xor(sq, o);
    }
    __shared__ float red[8];
    int w = tid >> 6;
    if ((tid & 63) == 0) { red[w] = s; red[4 + w] = sq; }
    __syncthreads();
    float ts = red[0] + red[1] + red[2] + red[3];
    float tq = red[4] + red[5] + red[6] + red[7];
    float mu  = ts * (1.f / DM);
    float var = tq * (1.f / DM) - mu * mu;
    float inv = rsqrtf(var + 1e-5f);
    __hip_bfloat16* o0 = xn + (size_t)row * DM;
    o0[tid]       = __float2bfloat16((v0 - mu) * inv * g[tid]       + be[tid]);
    o0[tid + 256] = __float2bfloat16((v1 - mu) * inv * g[tid + 256] + be[tid + 256]);
}

// ---------------- Transpose + cast: in fp32 [R][Cc] -> out bf16 [Cc][R], bounds-guarded ----
__global__ void transpose_cast(const float* __restrict__ in, __hip_bfloat16* __restrict__ out,
                               int R, int Cc) {
    __shared__ float tile[64][65];
    const float* inb = in + (size_t)blockIdx.z * R * Cc;
    __hip_bfloat16* outb = out + (size_t)blockIdx.z * R * Cc;
    int r0 = blockIdx.y * 64, c0 = blockIdx.x * 64;
    int tid = threadIdx.x;
    #pragma unroll
    for (int i = tid; i < 4096; i += 256) {
        int r = i >> 6, c = i & 63;
        tile[r][c] = (r0 + r < R && c0 + c < Cc) ? inb[(size_t)(r0 + r) * Cc + c0 + c] : 0.f;
    }
    __syncthreads();
    #pragma unroll
    for (int i = tid; i < 4096; i += 256) {
        int c = i >> 6, r = i & 63;
        if (r0 + r < R && c0 + c < Cc)
            outb[(size_t)(c0 + c) * R + r0 + r] = __float2bfloat16(tile[r][c]);
    }
}

// ---------------- bf16 MFMA GEMM: C(MxN) = A(MxK) * Bt(NxK)^T  [+ Res] ----------------
template<bool RES>
__global__ __launch_bounds__(256) void gemm_bf16(const __hip_bfloat16* __restrict__ A,
                                                 const __hip_bfloat16* __restrict__ Bt,
                                                 const float* __restrict__ Res,
                                                 float* __restrict__ C,
                                                 int M, int N, int K) {
    __shared__ __hip_bfloat16 As[128 * 32];
    __shared__ __hip_bfloat16 Bs[128 * 32];
    const int tid  = threadIdx.x;
    const int wave = tid >> 6, lane = tid & 63;
    const int m0 = blockIdx.y * 128, n0 = blockIdx.x * 128;
    const int wm = (wave >> 1) * 64, wn = (wave & 1) * 64;

    floatx4 acc[4][4] = {};

    const int arow16 = lane & 15;
    const int kgrp   = lane >> 4;

    for (int k0 = 0; k0 < K; k0 += 32) {
        #pragma unroll
        for (int r = 0; r < 2; ++r) {
            int i   = wave * 64 + r * 256 + lane;   // 0..511
            int row = i >> 2, seg = i & 3;
            int brow = n0 + row; if (brow >= N) brow = N - 1;
            const __hip_bfloat16* gA = A  + (size_t)(m0 + row) * K + k0 + seg * 8;
            const __hip_bfloat16* gB = Bt + (size_t)brow * K + k0 + seg * 8;
            __hip_bfloat16* lA = As + (size_t)(wave * 64 + r * 256) * 8;
            __hip_bfloat16* lB = Bs + (size_t)(wave * 64 + r * 256) * 8;
            __builtin_amdgcn_global_load_lds(
                (const __attribute__((address_space(1))) void*)gA,
                (__attribute__((address_space(3))) void*)lA, 16, 0, 0);
            __builtin_amdgcn_global_load_lds(
                (const __attribute__((address_space(1))) void*)gB,
                (__attribute__((address_space(3))) void*)lB, 16, 0, 0);
        }
        __syncthreads();

        const shortx8* Asv = (const shortx8*)As;
        const shortx8* Bsv = (const shortx8*)Bs;
        shortx8 a[4], b[4];
        #pragma unroll
        for (int i = 0; i < 4; ++i)
            a[i] = Asv[(wm + i * 16 + arow16) * 4 + kgrp];
        #pragma unroll
        for (int j = 0; j < 4; ++j)
            b[j] = Bsv[(wn + j * 16 + arow16) * 4 + kgrp];
        #pragma unroll
        for (int i = 0; i < 4; ++i)
            #pragma unroll
            for (int j = 0; j < 4; ++j)
                acc[i][j] = __builtin_amdgcn_mfma_f32_16x16x32_bf16(a[i], b[j], acc[i][j], 0, 0, 0);
        __syncthreads();
    }

    const int drow = (lane >> 4) * 4;
    const int dcol = lane & 15;
    #pragma unroll
    for (int i = 0; i < 4; ++i)
        #pragma unroll
        for (int j = 0; j < 4; ++j) {
            int rowb = m0 + wm + i * 16 + drow;
            int col  = n0 + wn + j * 16 + dcol;
            if (col < N) {
                #pragma unroll
                for (int r = 0; r < 4; ++r) {
                    size_t idx = (size_t)(rowb + r) * N + col;
                    float v = acc[i][j][r];
                    if (RES) v += Res[idx];
                    C[idx] = v;
                }
            }
        }
}

// ---------------- Causal depthwise conv (taps=4) + bias + SiLU, dual fp32/bf16 out -------
__global__ void conv_silu(const float* __restrict__ xz, const float* __restrict__ cw,
                          const float* __restrict__ cb, float* __restrict__ xcv,
                          __hip_bfloat16* __restrict__ xcv_bf) {
    int idx = blockIdx.x * 256 + threadIdx.x;   // (b*L + t)*DI + d
    int d = idx & (DI - 1);
    int bt = idx / DI;
    int t = bt & (Lseq - 1);
    int b = bt / Lseq;
    float acc = cb[d];
    #pragma unroll
    for (int k = 0; k < 4; ++k) {
        int tt = t - 3 + k;
        float xv = (tt >= 0) ? xz[((size_t)(b * Lseq + tt)) * (2 * DI) + d] : 0.f;
        acc += xv * cw[d * 4 + k];
    }
    float v = silu_f(acc);
    xcv[idx] = v;
    xcv_bf[idx] = __float2bfloat16(v);
}

// ---------------- delta = softplus(dt @ W_dt + b_dt) ----------------
__global__ void delta_kernel(const float* __restrict__ xdb, const float* __restrict__ Wdt,
                             const float* __restrict__ bdt, float* __restrict__ delta) {
    int row = blockIdx.y;
    int d = blockIdx.x * 256 + threadIdx.x;
    __shared__ float dtv[RNK];
    if (threadIdx.x < RNK) dtv[threadIdx.x] = xdb[(size_t)row * XDBW + threadIdx.x];
    __syncthreads();
    float acc = bdt[d];
    #pragma unroll
    for (int r = 0; r < RNK; ++r) acc += dtv[r] * Wdt[(size_t)r * DI + d];
    float sp = (acc > 20.f) ? acc : log1pf(__expf(acc));
    delta[(size_t)row * DI + d] = sp;
}

// ============ Chunked scan, phase 1: local scan per chunk (h0=0) + chunk delta-sum =======
// block: 512 thr = 8 waves; wave w handles d = dbase + {2w, 2w+1}; lane = state s.
// grid: (b*NC + c) * (DI/16) + dg
__global__ __launch_bounds__(512) void scan_chunk1(
        const float* __restrict__ delta, const float* __restrict__ xcv,
        const float* __restrict__ xdb, const float* __restrict__ A_log,
        float* __restrict__ hend, float* __restrict__ dsum) {
    __shared__ float Bsh[64][68];     // [s][t], b128-readable along t
    __shared__ float2 dxsh[16][65];   // [dd][t] = (delta, delta*x)

    int blk = blockIdx.x;
    int dg = blk & 63, bc = blk >> 6;
    int c = bc & (NC - 1), b = bc >> 4;
    int tid = threadIdx.x, w = tid >> 6, lane = tid & 63;
    int dbase = dg * 16;
    int r0 = b * Lseq + c * CH;

    // stage B transposed: [t][s] global -> [s][t] LDS
    #pragma unroll
    for (int k = 0; k < 2; ++k) {
        int i = tid + k * 512;          // 0..1023
        int t = i >> 4, sg = i & 15;
        float4 v = *(const float4*)&xdb[(size_t)(r0 + t) * XDBW + RNK + sg * 4];
        Bsh[sg * 4 + 0][t] = v.x; Bsh[sg * 4 + 1][t] = v.y;
        Bsh[sg * 4 + 2][t] = v.z; Bsh[sg * 4 + 3][t] = v.w;
    }
    // stage delta, delta*x per (dd, t)
    #pragma unroll
    for (int k = 0; k < 2; ++k) {
        int i = tid + k * 512;
        int dd = i & 15, t = i >> 4;
        float dv = delta[(size_t)(r0 + t) * DI + dbase + dd];
        float xv = xcv[(size_t)(r0 + t) * DI + dbase + dd];
        dxsh[dd][t] = make_float2(dv, dv * xv);
    }
    __syncthreads();

    int d0 = dbase + 2 * w, d1 = d0 + 1;
    float a0 = -__expf(A_log[d0 * DS + lane]);
    float a1 = -__expf(A_log[d1 * DS + lane]);
    float2 vdx0 = dxsh[2 * w][lane];
    float2 vdx1 = dxsh[2 * w + 1][lane];
    float h0 = 0.f, h1 = 0.f;

    #pragma unroll
    for (int t0 = 0; t0 < CH; t0 += 4) {
        float4 Bv = *(const float4*)&Bsh[lane][t0];
        #pragma unroll
        for (int j = 0; j < 4; ++j) {
            int t = t0 + j;
            float dt0 = rdl(vdx0.x, t), px0 = rdl(vdx0.y, t);
            float dt1 = rdl(vdx1.x, t), px1 = rdl(vdx1.y, t);
            float Bj = (&Bv.x)[j];
            h0 = h0 * __expf(dt0 * a0) + px0 * Bj;
            h1 = h1 * __expf(dt1 * a1) + px1 * Bj;
        }
    }

    float S0 = vdx0.x, S1 = vdx1.x;
    #pragma unroll
    for (int o = 1; o < 64; o <<= 1) {
        S0 += __shfl_xor(S0, o);
        S1 += __shfl_xor(S1, o);
    }
    size_t base0 = ((size_t)bc * DI + d0) * 64;
    size_t base1 = ((size_t)bc * DI + d1) * 64;
    hend[base0 + lane] = h0;
    hend[base1 + lane] = h1;
    if (lane == 0) {
        dsum[(size_t)bc * DI + d0] = S0;
        dsum[(size_t)bc * DI + d1] = S1;
    }
}

// ============ Chunked scan, phase 2: stitch across chunks ============
__global__ __launch_bounds__(256) void scan_stitch(
        const float* __restrict__ hend, const float* __restrict__ dsum,
        const float* __restrict__ A_log, float* __restrict__ hstart) {
    int idx = blockIdx.x * 4 + (threadIdx.x >> 6);   // b*DI + d
    int lane = threadIdx.x & 63;
    int b = idx >> 10, d = idx & (DI - 1);
    float a = -__expf(A_log[d * DS + lane]);
    float h = 0.f;
    #pragma unroll
    for (int c = 0; c < NC; ++c) {
        size_t base = ((size_t)(b * NC + c) * DI + d) * 64;
        hstart[base + lane] = h;
        float he = hend[base + lane];
        float S  = dsum[(size_t)(b * NC + c) * DI + d];
        h = he + __expf(a * S) * h;
    }
}

// ============ Chunked scan, phase 3: recompute with correct h_start, emit y ============
__global__ __launch_bounds__(512) void scan_chunk2(
        const float* __restrict__ delta, const float* __restrict__ xcv,
        const float* __restrict__ xdb, const float* __restrict__ xz,
        const float* __restrict__ A_log, const float* __restrict__ Dp,
        const float* __restrict__ hstart, float* __restrict__ yT) {
    __shared__ float Bsh[64][68];     // [s][t]
    __shared__ float Csh[64][68];     // [s][t]
    __shared__ float2 dxsh[16][65];   // [dd][t] = (delta, delta*x)
    __shared__ float2 exsh[16][65];   // [dd][t] = (x, z)
    __shared__ float P[8][2][16][12]; // [wave][d-pair][s-quad k][t within 8, pad 12]

    int blk = blockIdx.x;
    int dg = blk & 63, bc = blk >> 6;
    int c = bc & (NC - 1), b = bc >> 4;
    int tid = threadIdx.x, w = tid >> 6, lane = tid & 63;
    int dbase = dg * 16;
    int r0 = b * Lseq + c * CH;

    // stage B and C transposed
    #pragma unroll
    for (int k = 0; k < 4; ++k) {
        int i = tid + k * 512;          // 0..2047
        int t = i >> 5, sg = i & 31;
        float4 v = *(const float4*)&xdb[(size_t)(r0 + t) * XDBW + RNK + sg * 4];
        if (sg < 16) {
            Bsh[sg * 4 + 0][t] = v.x; Bsh[sg * 4 + 1][t] = v.y;
            Bsh[sg * 4 + 2][t] = v.z; Bsh[sg * 4 + 3][t] = v.w;
        } else {
            int s0 = (sg - 16) * 4;
            Csh[s0 + 0][t] = v.x; Csh[s0 + 1][t] = v.y;
            Csh[s0 + 2][t] = v.z; Csh[s0 + 3][t] = v.w;
        }
    }
    #pragma unroll
    for (int k = 0; k < 2; ++k) {
        int i = tid + k * 512;
        int dd = i & 15, t = i >> 4;
        float dv = delta[(size_t)(r0 + t) * DI + dbase + dd];
        float xv = xcv[(size_t)(r0 + t) * DI + dbase + dd];
        float zv = xz[(size_t)(r0 + t) * (2 * DI) + DI + dbase + dd];
        dxsh[dd][t] = make_float2(dv, dv * xv);
        exsh[dd][t] = make_float2(xv, zv);
    }
    __syncthreads();

    int d0 = dbase + 2 * w, d1 = d0 + 1;
    float a0 = -__expf(A_log[d0 * DS + lane]);
    float a1 = -__expf(A_log[d1 * DS + lane]);
    float Dv0 = Dp[d0], Dv1 = Dp[d1];
    float2 vdx0 = dxsh[2 * w][lane];
    float2 vdx1 = dxsh[2 * w + 1][lane];
    float h0 = hstart[((size_t)bc * DI + d0) * 64 + lane];
    float h1 = hstart[((size_t)bc * DI + d1) * 64 + lane];

    const int tr = lane & 7, q = (lane >> 3) & 3, dd = lane >> 5;

    #pragma unroll
    for (int t8 = 0; t8 < 8; ++t8) {
        #pragma unroll
        for (int th = 0; th < 2; ++th) {
            int t0 = t8 * 8 + th * 4;
            float4 Bv = *(const float4*)&Bsh[lane][t0];
            float4 Cv = *(const float4*)&Csh[lane][t0];
            float4 pk0, pk1;
            #pragma unroll
            for (int j = 0; j < 4; ++j) {
                int t = t0 + j;
                float dt0 = rdl(vdx0.x, t), px0 = rdl(vdx0.y, t);
                float dt1 = rdl(vdx1.x, t), px1 = rdl(vdx1.y, t);
                float Bj = (&Bv.x)[j], Cj = (&Cv.x)[j];
                h0 = h0 * __expf(dt0 * a0) + px0 * Bj;
                h1 = h1 * __expf(dt1 * a1) + px1 * Bj;
                (&pk0.x)[j] = dpp_add2(h0 * Cj);
                (&pk1.x)[j] = dpp_add2(h1 * Cj);
            }
            if ((lane & 3) == 0) {
                int k = lane >> 2;
                *(float4*)&P[w][0][k][th * 4] = pk0;
                *(float4*)&P[w][1][k][th * 4] = pk1;
            }
        }
        // reduce the 8 t's: sum 16 s-quad partials per (dd, t)
        float sacc = 0.f;
        #pragma unroll
        for (int j = 0; j < 4; ++j) sacc += P[w][dd][q * 4 + j][tr];
        sacc += __shfl_xor(sacc, 8);
        sacc += __shfl_xor(sacc, 16);
        if (q == 0) {
            int t = t8 * 8 + tr;
            float2 xzv = exsh[2 * w + dd][t];
            float Dv = dd ? Dv1 : Dv0;
            float yv = (sacc + xzv.x * Dv) * silu_f(xzv.y);
            yT[((size_t)(b * DI + dbase + 2 * w + dd)) * Lseq + c * CH + t] = yv;
        }
    }
}

extern "C" void kernel_launch(void* const* d_in, const int* in_sizes, int n_in,
                              void* d_out, int out_size, void* d_ws, size_t ws_size,
                              hipStream_t stream) {
    const float* frames = (const float*)d_in[0];
    const float* gamma  = (const float*)d_in[1];
    const float* beta   = (const float*)d_in[2];
    const float* W_in   = (const float*)d_in[3];
    const float* conv_w = (const float*)d_in[4];
    const float* conv_b = (const float*)d_in[5];
    const float* W_x    = (const float*)d_in[6];
    const float* W_dt   = (const float*)d_in[7];
    const float* b_dt   = (const float*)d_in[8];
    const float* A_log  = (const float*)d_in[9];
    const float* Dp     = (const float*)d_in[10];
    const float* W_out  = (const float*)d_in[11];
    float* out = (float*)d_out;

    // workspace carve-up (bytes)
    char* ws = (char*)d_ws;
    __hip_bfloat16* xn_bf  = (__hip_bfloat16*)ws; ws += (size_t)NROWS * DM * 2;
    __hip_bfloat16* Wt_in  = (__hip_bfloat16*)ws; ws += (size_t)(2 * DI) * DM * 2;
    __hip_bfloat16* Wt_out = (__hip_bfloat16*)ws; ws += (size_t)DM * DI * 2;
    __hip_bfloat16* Wt_x   = (__hip_bfloat16*)ws; ws += (size_t)XDBW * DI * 2;
    __hip_bfloat16* y_row  = (__hip_bfloat16*)ws; ws += (size_t)NROWS * DI * 2;
    __hip_bfloat16* xcv_bf = (__hip_bfloat16*)ws; ws += (size_t)NROWS * DI * 2;
    float* xz     = (float*)ws;  ws += (size_t)NROWS * 2 * DI * 4;
    float* xcv    = (float*)ws;  ws += (size_t)NROWS * DI * 4;
    float* xdb    = (float*)ws;  ws += (size_t)NROWS * XDBW * 4;
    float* delta  = (float*)ws;  ws += (size_t)NROWS * DI * 4;
    float* yT     = (float*)ws;  ws += (size_t)NROWS * DI * 4;
    float* hend   = (float*)ws;  ws += (size_t)Bn * NC * DI * 64 * 4;
    float* hstart = (float*)ws;  ws += (size_t)Bn * NC * DI * 64 * 4;
    float* dsum   = (float*)ws;  ws += (size_t)Bn * NC * DI * 4;

    // weight cast+transpose
    transpose_cast<<<dim3(2 * DI / 64, DM / 64, 1), 256, 0, stream>>>(W_in, Wt_in, DM, 2 * DI);
    transpose_cast<<<dim3(DM / 64, DI / 64, 1), 256, 0, stream>>>(W_out, Wt_out, DI, DM);
    transpose_cast<<<dim3((XDBW + 63) / 64, DI / 64, 1), 256, 0, stream>>>(W_x, Wt_x, DI, XDBW);

    ln_kernel<<<NROWS, 256, 0, stream>>>(frames, gamma, beta, xn_bf);

    // in_proj: xz = xn @ W_in  (M=2048, N=2048, K=512)
    gemm_bf16<false><<<dim3(2 * DI / 128, NROWS / 128), 256, 0, stream>>>(
        xn_bf, Wt_in, nullptr, xz, NROWS, 2 * DI, DM);

    conv_silu<<<(NROWS * DI) / 256, 256, 0, stream>>>(xz, conv_w, conv_b, xcv, xcv_bf);

    // xdb = xcv @ W_x  (M=2048, N=160, K=1024) via MFMA, guarded N
    gemm_bf16<false><<<dim3((XDBW + 127) / 128, NROWS / 128), 256, 0, stream>>>(
        xcv_bf, Wt_x, nullptr, xdb, NROWS, XDBW, DI);

    delta_kernel<<<dim3(DI / 256, NROWS), 256, 0, stream>>>(xdb, W_dt, b_dt, delta);

    // chunked selective scan (2 d-channels per wave)
    scan_chunk1<<<Bn * NC * (DI / 16), 512, 0, stream>>>(delta, xcv, xdb, A_log, hend, dsum);
    scan_stitch<<<Bn * DI / 4, 256, 0, stream>>>(hend, dsum, A_log, hstart);
    scan_chunk2<<<Bn * NC * (DI / 16), 512, 0, stream>>>(delta, xcv, xdb, xz, A_log, Dp, hstart, yT);

    // yT [b][1024 d][1024 t] -> y_row bf16 [b*L + t][d]
    transpose_cast<<<dim3(Lseq / 64, DI / 64, Bn), 256, 0, stream>>>(yT, y_row, DI, Lseq);

    // out_proj: out = y_row @ W_out + frames  (M=2048, N=512, K=1024)
    gemm_bf16<true><<<dim3(DM / 128, NROWS / 128), 256, 0, stream>>>(
        y_row, Wt_out, frames, out, NROWS, DM, DI);
}

// Round 6
// 296.027 us; speedup vs baseline: 1.0279x; 1.0279x over previous
//
#include <hip/hip_runtime.h>
#include <hip/hip_bf16.h>
#include <math.h>

// Problem constants
constexpr int Bn     = 2;
constexpr int Lseq   = 1024;
constexpr int DM     = 512;    // d_model
constexpr int DI     = 1024;   // d_inner
constexpr int DS     = 64;     // d_state
constexpr int RNK    = 32;     // dt_rank
constexpr int NROWS  = Bn * Lseq;  // 2048
constexpr int XDBW   = RNK + 2 * DS; // 160
constexpr int CH     = 64;     // scan chunk length
constexpr int NC     = Lseq / CH;  // 16 chunks

typedef __attribute__((ext_vector_type(4))) float floatx4;
typedef __attribute__((ext_vector_type(8))) short shortx8;

__device__ __forceinline__ float silu_f(float v) {
    return v / (1.f + __expf(-v));
}

// ---------------- LayerNorm -> bf16 ----------------
__global__ void ln_kernel(const float* __restrict__ x, const float* __restrict__ g,
                          const float* __restrict__ be, __hip_bfloat16* __restrict__ xn) {
    int row = blockIdx.x;
    int tid = threadIdx.x;
    const float* xr = x + (size_t)row * DM;
    float v0 = xr[tid], v1 = xr[tid + 256];
    float s = v0 + v1, sq = v0 * v0 + v1 * v1;
    #pragma unroll
    for (int o = 1; o < 64; o <<= 1) {
        s  += __shfl_xor(s, o);
        sq += __shfl_xor(sq, o);
    }
    __shared__ float red[8];
    int w = tid >> 6;
    if ((tid & 63) == 0) { red[w] = s; red[4 + w] = sq; }
    __syncthreads();
    float ts = red[0] + red[1] + red[2] + red[3];
    float tq = red[4] + red[5] + red[6] + red[7];
    float mu  = ts * (1.f / DM);
    float var = tq * (1.f / DM) - mu * mu;
    float inv = rsqrtf(var + 1e-5f);
    __hip_bfloat16* o0 = xn + (size_t)row * DM;
    o0[tid]       = __float2bfloat16((v0 - mu) * inv * g[tid]       + be[tid]);
    o0[tid + 256] = __float2bfloat16((v1 - mu) * inv * g[tid + 256] + be[tid + 256]);
}

// ---------------- Transpose + cast: in fp32 [R][Cc] -> out bf16 [Cc][R], bounds-guarded ----
__global__ void transpose_cast(const float* __restrict__ in, __hip_bfloat16* __restrict__ out,
                               int R, int Cc) {
    __shared__ float tile[64][65];
    const float* inb = in + (size_t)blockIdx.z * R * Cc;
    __hip_bfloat16* outb = out + (size_t)blockIdx.z * R * Cc;
    int r0 = blockIdx.y * 64, c0 = blockIdx.x * 64;
    int tid = threadIdx.x;
    #pragma unroll
    for (int i = tid; i < 4096; i += 256) {
        int r = i >> 6, c = i & 63;
        tile[r][c] = (r0 + r < R && c0 + c < Cc) ? inb[(size_t)(r0 + r) * Cc + c0 + c] : 0.f;
    }
    __syncthreads();
    #pragma unroll
    for (int i = tid; i < 4096; i += 256) {
        int c = i >> 6, r = i & 63;
        if (r0 + r < R && c0 + c < Cc)
            outb[(size_t)(c0 + c) * R + r0 + r] = __float2bfloat16(tile[r][c]);
    }
}

// ---------------- bf16 MFMA GEMM: C(MxN) = A(MxK) * Bt(NxK)^T  [+ Res] ----------------
template<bool RES>
__global__ __launch_bounds__(256) void gemm_bf16(const __hip_bfloat16* __restrict__ A,
                                                 const __hip_bfloat16* __restrict__ Bt,
                                                 const float* __restrict__ Res,
                                                 float* __restrict__ C,
                                                 int M, int N, int K) {
    __shared__ __hip_bfloat16 As[128 * 32];
    __shared__ __hip_bfloat16 Bs[128 * 32];
    const int tid  = threadIdx.x;
    const int wave = tid >> 6, lane = tid & 63;
    const int m0 = blockIdx.y * 128, n0 = blockIdx.x * 128;
    const int wm = (wave >> 1) * 64, wn = (wave & 1) * 64;

    floatx4 acc[4][4] = {};

    const int arow16 = lane & 15;
    const int kgrp   = lane >> 4;

    for (int k0 = 0; k0 < K; k0 += 32) {
        #pragma unroll
        for (int r = 0; r < 2; ++r) {
            int i   = wave * 64 + r * 256 + lane;   // 0..511
            int row = i >> 2, seg = i & 3;
            int brow = n0 + row; if (brow >= N) brow = N - 1;
            const __hip_bfloat16* gA = A  + (size_t)(m0 + row) * K + k0 + seg * 8;
            const __hip_bfloat16* gB = Bt + (size_t)brow * K + k0 + seg * 8;
            __hip_bfloat16* lA = As + (size_t)(wave * 64 + r * 256) * 8;
            __hip_bfloat16* lB = Bs + (size_t)(wave * 64 + r * 256) * 8;
            __builtin_amdgcn_global_load_lds(
                (const __attribute__((address_space(1))) void*)gA,
                (__attribute__((address_space(3))) void*)lA, 16, 0, 0);
            __builtin_amdgcn_global_load_lds(
                (const __attribute__((address_space(1))) void*)gB,
                (__attribute__((address_space(3))) void*)lB, 16, 0, 0);
        }
        __syncthreads();

        const shortx8* Asv = (const shortx8*)As;
        const shortx8* Bsv = (const shortx8*)Bs;
        shortx8 a[4], b[4];
        #pragma unroll
        for (int i = 0; i < 4; ++i)
            a[i] = Asv[(wm + i * 16 + arow16) * 4 + kgrp];
        #pragma unroll
        for (int j = 0; j < 4; ++j)
            b[j] = Bsv[(wn + j * 16 + arow16) * 4 + kgrp];
        #pragma unroll
        for (int i = 0; i < 4; ++i)
            #pragma unroll
            for (int j = 0; j < 4; ++j)
                acc[i][j] = __builtin_amdgcn_mfma_f32_16x16x32_bf16(a[i], b[j], acc[i][j], 0, 0, 0);
        __syncthreads();
    }

    const int drow = (lane >> 4) * 4;
    const int dcol = lane & 15;
    #pragma unroll
    for (int i = 0; i < 4; ++i)
        #pragma unroll
        for (int j = 0; j < 4; ++j) {
            int rowb = m0 + wm + i * 16 + drow;
            int col  = n0 + wn + j * 16 + dcol;
            if (col < N) {
                #pragma unroll
                for (int r = 0; r < 4; ++r) {
                    size_t idx = (size_t)(rowb + r) * N + col;
                    float v = acc[i][j][r];
                    if (RES) v += Res[idx];
                    C[idx] = v;
                }
            }
        }
}

// ---------------- Causal depthwise conv (taps=4) + bias + SiLU, dual fp32/bf16 out -------
__global__ void conv_silu(const float* __restrict__ xz, const float* __restrict__ cw,
                          const float* __restrict__ cb, float* __restrict__ xcv,
                          __hip_bfloat16* __restrict__ xcv_bf) {
    int idx = blockIdx.x * 256 + threadIdx.x;   // (b*L + t)*DI + d
    int d = idx & (DI - 1);
    int bt = idx / DI;
    int t = bt & (Lseq - 1);
    int b = bt / Lseq;
    float acc = cb[d];
    #pragma unroll
    for (int k = 0; k < 4; ++k) {
        int tt = t - 3 + k;
        float xv = (tt >= 0) ? xz[((size_t)(b * Lseq + tt)) * (2 * DI) + d] : 0.f;
        acc += xv * cw[d * 4 + k];
    }
    float v = silu_f(acc);
    xcv[idx] = v;
    xcv_bf[idx] = __float2bfloat16(v);
}

// ---------------- delta = softplus(dt @ W_dt + b_dt) ----------------
__global__ void delta_kernel(const float* __restrict__ xdb, const float* __restrict__ Wdt,
                             const float* __restrict__ bdt, float* __restrict__ delta) {
    int row = blockIdx.y;
    int d = blockIdx.x * 256 + threadIdx.x;
    __shared__ float dtv[RNK];
    if (threadIdx.x < RNK) dtv[threadIdx.x] = xdb[(size_t)row * XDBW + threadIdx.x];
    __syncthreads();
    float acc = bdt[d];
    #pragma unroll
    for (int r = 0; r < RNK; ++r) acc += dtv[r] * Wdt[(size_t)r * DI + d];
    float sp = (acc > 20.f) ? acc : log1pf(__expf(acc));
    delta[(size_t)row * DI + d] = sp;
}

// ============ Chunked scan, phase 1: local scan per chunk (h0=0) + chunk delta-sum =======
// block: 512 thr = 8 waves; wave w handles d = dg*8+w, lane = state s.
// grid: (b*NC + c) * (DI/8) + dg
__global__ __launch_bounds__(512) void scan_chunk1(
        const float* __restrict__ delta, const float* __restrict__ xcv,
        const float* __restrict__ xdb, const float* __restrict__ A_log,
        float* __restrict__ hend, float* __restrict__ dsum) {
    __shared__ float Bsh[64][68];
    __shared__ float dsh[8][64];
    __shared__ float xsh[8][64];

    int blk = blockIdx.x;
    int dg  = blk & (DI / 8 - 1);   // 0..127
    int bc  = blk >> 7;             // b*NC + c
    int c = bc & (NC - 1), b = bc >> 4;
    int tid = threadIdx.x, w = tid >> 6, lane = tid & 63;
    int d = dg * 8 + w;
    int r0 = b * Lseq + c * CH;

    // stage B (cols 32..95 of xdb), float4
    #pragma unroll
    for (int k = 0; k < 2; ++k) {
        int idx = tid + k * 512;          // 0..1023
        int row = idx >> 4, j4 = idx & 15;
        float4 v = *(const float4*)&xdb[(size_t)(r0 + row) * XDBW + RNK + j4 * 4];
        *(float4*)&Bsh[row][j4 * 4] = v;
    }
    {
        int t = tid >> 3, ww = tid & 7;
        dsh[ww][t] = delta[(size_t)(r0 + t) * DI + dg * 8 + ww];
        xsh[ww][t] = xcv[(size_t)(r0 + t) * DI + dg * 8 + ww];
    }
    __syncthreads();

    float a = -__expf(A_log[d * DS + lane]);
    float h = 0.f, S = 0.f;
    #pragma unroll
    for (int t = 0; t < CH; ++t) {
        float dt_ = dsh[w][t];
        float e = __expf(dt_ * a);
        S += dt_;
        h = h * e + (dt_ * xsh[w][t]) * Bsh[t][lane];
    }
    size_t base = ((size_t)bc * DI + d) * 64;
    hend[base + lane] = h;
    if (lane == 0) dsum[(size_t)bc * DI + d] = S;
}

// ============ Chunked scan, phase 2: stitch across chunks ============
// wave per (b,d), lane = s; 16 sequential chunk steps.
__global__ __launch_bounds__(256) void scan_stitch(
        const float* __restrict__ hend, const float* __restrict__ dsum,
        const float* __restrict__ A_log, float* __restrict__ hstart) {
    int idx = blockIdx.x * 4 + (threadIdx.x >> 6);   // b*DI + d
    int lane = threadIdx.x & 63;
    int b = idx >> 10, d = idx & (DI - 1);
    float a = -__expf(A_log[d * DS + lane]);
    float h = 0.f;
    #pragma unroll
    for (int c = 0; c < NC; ++c) {
        size_t base = ((size_t)(b * NC + c) * DI + d) * 64;
        hstart[base + lane] = h;
        float he = hend[base + lane];
        float S  = dsum[(size_t)(b * NC + c) * DI + d];
        h = he + __expf(a * S) * h;
    }
}

// ============ Chunked scan, phase 3: recompute with correct h_start, emit y ============
// P row stride 69: reduce-read bank = (5*tr + 16*q + j) mod 32 -> max 2 lanes/bank (free).
__global__ __launch_bounds__(512) void scan_chunk2(
        const float* __restrict__ delta, const float* __restrict__ xcv,
        const float* __restrict__ xdb, const float* __restrict__ xz,
        const float* __restrict__ A_log, const float* __restrict__ Dp,
        const float* __restrict__ hstart, float* __restrict__ yT) {
    __shared__ float Bsh[64][68];
    __shared__ float Csh[64][68];
    __shared__ float dsh[8][64];
    __shared__ float xsh[8][64];
    __shared__ float zsh[8][64];
    __shared__ float P[8][16 * 69];

    int blk = blockIdx.x;
    int dg  = blk & (DI / 8 - 1);
    int bc  = blk >> 7;
    int c = bc & (NC - 1), b = bc >> 4;
    int tid = threadIdx.x, w = tid >> 6, lane = tid & 63;
    int d = dg * 8 + w;
    int r0 = b * Lseq + c * CH;

    // stage B and C (cols 32..159 of xdb), float4
    #pragma unroll
    for (int k = 0; k < 4; ++k) {
        int idx = tid + k * 512;          // 0..2047
        int row = idx >> 5, j4 = idx & 31;
        float4 v = *(const float4*)&xdb[(size_t)(r0 + row) * XDBW + RNK + j4 * 4];
        if (j4 < 16) *(float4*)&Bsh[row][j4 * 4] = v;
        else         *(float4*)&Csh[row][(j4 - 16) * 4] = v;
    }
    {
        int t = tid >> 3, ww = tid & 7;
        dsh[ww][t] = delta[(size_t)(r0 + t) * DI + dg * 8 + ww];
        xsh[ww][t] = xcv[(size_t)(r0 + t) * DI + dg * 8 + ww];
        zsh[ww][t] = xz[(size_t)(r0 + t) * (2 * DI) + DI + dg * 8 + ww];
    }
    __syncthreads();

    float a  = -__expf(A_log[d * DS + lane]);
    float Dv = Dp[d];
    size_t base = ((size_t)bc * DI + d) * 64;
    float h = hstart[base + lane];
    float* Pw = P[w];

    #pragma unroll
    for (int t16 = 0; t16 < 4; ++t16) {
        #pragma unroll
        for (int tt = 0; tt < 16; ++tt) {
            int t = t16 * 16 + tt;
            float dt_ = dsh[w][t];
            float e = __expf(dt_ * a);
            h = h * e + (dt_ * xsh[w][t]) * Bsh[t][lane];
            Pw[tt * 69 + lane] = h * Csh[t][lane];
        }
        // per-wave reduce: lane = (q=lane>>4, tr=lane&15); sum over s
        float sacc = 0.f;
        int tr = lane & 15, q = lane >> 4;
        #pragma unroll
        for (int j = 0; j < 16; ++j) sacc += Pw[tr * 69 + q * 16 + j];
        sacc += __shfl_xor(sacc, 16);
        sacc += __shfl_xor(sacc, 32);
        if (lane < 16) {
            int t = t16 * 16 + lane;
            float yv = (sacc + xsh[w][t] * Dv) * silu_f(zsh[w][t]);
            yT[((size_t)(b * DI + d)) * Lseq + c * CH + t] = yv;
        }
    }
}

extern "C" void kernel_launch(void* const* d_in, const int* in_sizes, int n_in,
                              void* d_out, int out_size, void* d_ws, size_t ws_size,
                              hipStream_t stream) {
    const float* frames = (const float*)d_in[0];
    const float* gamma  = (const float*)d_in[1];
    const float* beta   = (const float*)d_in[2];
    const float* W_in   = (const float*)d_in[3];
    const float* conv_w = (const float*)d_in[4];
    const float* conv_b = (const float*)d_in[5];
    const float* W_x    = (const float*)d_in[6];
    const float* W_dt   = (const float*)d_in[7];
    const float* b_dt   = (const float*)d_in[8];
    const float* A_log  = (const float*)d_in[9];
    const float* Dp     = (const float*)d_in[10];
    const float* W_out  = (const float*)d_in[11];
    float* out = (float*)d_out;

    // workspace carve-up (bytes)
    char* ws = (char*)d_ws;
    __hip_bfloat16* xn_bf  = (__hip_bfloat16*)ws; ws += (size_t)NROWS * DM * 2;
    __hip_bfloat16* Wt_in  = (__hip_bfloat16*)ws; ws += (size_t)(2 * DI) * DM * 2;
    __hip_bfloat16* Wt_out = (__hip_bfloat16*)ws; ws += (size_t)DM * DI * 2;
    __hip_bfloat16* Wt_x   = (__hip_bfloat16*)ws; ws += (size_t)XDBW * DI * 2;
    __hip_bfloat16* y_row  = (__hip_bfloat16*)ws; ws += (size_t)NROWS * DI * 2;
    __hip_bfloat16* xcv_bf = (__hip_bfloat16*)ws; ws += (size_t)NROWS * DI * 2;
    float* xz     = (float*)ws;  ws += (size_t)NROWS * 2 * DI * 4;
    float* xcv    = (float*)ws;  ws += (size_t)NROWS * DI * 4;
    float* xdb    = (float*)ws;  ws += (size_t)NROWS * XDBW * 4;
    float* delta  = (float*)ws;  ws += (size_t)NROWS * DI * 4;
    float* yT     = (float*)ws;  ws += (size_t)NROWS * DI * 4;
    float* hend   = (float*)ws;  ws += (size_t)Bn * NC * DI * 64 * 4;
    float* hstart = (float*)ws;  ws += (size_t)Bn * NC * DI * 64 * 4;
    float* dsum   = (float*)ws;  ws += (size_t)Bn * NC * DI * 4;

    // weight cast+transpose
    transpose_cast<<<dim3(2 * DI / 64, DM / 64, 1), 256, 0, stream>>>(W_in, Wt_in, DM, 2 * DI);
    transpose_cast<<<dim3(DM / 64, DI / 64, 1), 256, 0, stream>>>(W_out, Wt_out, DI, DM);
    transpose_cast<<<dim3((XDBW + 63) / 64, DI / 64, 1), 256, 0, stream>>>(W_x, Wt_x, DI, XDBW);

    ln_kernel<<<NROWS, 256, 0, stream>>>(frames, gamma, beta, xn_bf);

    // in_proj: xz = xn @ W_in  (M=2048, N=2048, K=512)
    gemm_bf16<false><<<dim3(2 * DI / 128, NROWS / 128), 256, 0, stream>>>(
        xn_bf, Wt_in, nullptr, xz, NROWS, 2 * DI, DM);

    conv_silu<<<(NROWS * DI) / 256, 256, 0, stream>>>(xz, conv_w, conv_b, xcv, xcv_bf);

    // xdb = xcv @ W_x  (M=2048, N=160, K=1024) via MFMA, guarded N
    gemm_bf16<false><<<dim3((XDBW + 127) / 128, NROWS / 128), 256, 0, stream>>>(
        xcv_bf, Wt_x, nullptr, xdb, NROWS, XDBW, DI);

    delta_kernel<<<dim3(DI / 256, NROWS), 256, 0, stream>>>(xdb, W_dt, b_dt, delta);

    // chunked selective scan
    scan_chunk1<<<Bn * NC * (DI / 8), 512, 0, stream>>>(delta, xcv, xdb, A_log, hend, dsum);
    scan_stitch<<<Bn * DI / 4, 256, 0, stream>>>(hend, dsum, A_log, hstart);
    scan_chunk2<<<Bn * NC * (DI / 8), 512, 0, stream>>>(delta, xcv, xdb, xz, A_log, Dp, hstart, yT);

    // yT [b][1024 d][1024 t] -> y_row bf16 [b*L + t][d]
    transpose_cast<<<dim3(Lseq / 64, DI / 64, Bn), 256, 0, stream>>>(yT, y_row, DI, Lseq);

    // out_proj: out = y_row @ W_out + frames  (M=2048, N=512, K=1024)
    gemm_bf16<true><<<dim3(DM / 128, NROWS / 128), 256, 0, stream>>>(
        y_row, Wt_out, frames, out, NROWS, DM, DI);
}